// Round 24
// baseline (1351.001 us; speedup 1.0000x reference)
//
#include <hip/hip_runtime.h>
#include <hip/hip_bf16.h>

#define EPSV 1e-5f
constexpr int NB = 32;

typedef short bf16x8 __attribute__((ext_vector_type(8)));
typedef short short4v __attribute__((ext_vector_type(4)));
typedef float f32x4 __attribute__((ext_vector_type(4)));

__device__ inline float bf2f(short s) {
  return __uint_as_float(((unsigned)(unsigned short)s) << 16);
}
__device__ inline short f2bf(float f) {
  unsigned u = __float_as_uint(f);
  unsigned r = (u + 0x7FFFu + ((u >> 16) & 1u)) >> 16;
  return (short)r;
}

// ---------------- x stats (NCDHW, C=1) ----------------
__global__ __launch_bounds__(256) void reduce_partial_f32(
    const float* __restrict__ in, int spatial, float* __restrict__ part,
    int totb, int boff)
{
  const int b = blockIdx.x;
  const int nblk = gridDim.x;
  float s = 0.f, s2 = 0.f;
  for (int n = 0; n < NB; ++n) {
    const float* p = in + (size_t)n * spatial;
    for (int i = b * 256 + threadIdx.x; i < spatial; i += nblk * 256) {
      float v = p[i];
      s += v; s2 += v * v;
    }
  }
  __shared__ float sh[256], sh2[256];
  int tid = threadIdx.x;
  sh[tid] = s; sh2[tid] = s2;
  __syncthreads();
  for (int off = 128; off > 0; off >>= 1) {
    if (tid < off) { sh[tid] += sh[tid + off]; sh2[tid] += sh2[tid + off]; }
    __syncthreads();
  }
  if (tid == 0) {
    part[(size_t)(boff + b) * 2 + 0] = sh[0];
    part[(size_t)(boff + b) * 2 + 1] = sh2[0];
  }
}

// ---------------- channels-last (rowlen 64) per-channel stats --------------
__global__ __launch_bounds__(256) void reduce_cl(
    const short* __restrict__ y, long nrows,
    float* __restrict__ part, int totb, int boff)
{
  const int b = blockIdx.x, nblk = gridDim.x;
  const int c = threadIdx.x & 63, seg = threadIdx.x >> 6;
  float s = 0.f, s2 = 0.f;
  for (long r = (long)b * 4 + seg; r < nrows; r += (long)nblk * 4) {
    float v = bf2f(y[r * 64 + c]);
    s += v; s2 += v * v;
  }
  __shared__ float sh[4][64], sh2[4][64];
  sh[seg][c] = s; sh2[seg][c] = s2;
  __syncthreads();
  if (seg == 0) {
    float a = sh[0][c] + sh[1][c] + sh[2][c] + sh[3][c];
    float a2 = sh2[0][c] + sh2[1][c] + sh2[2][c] + sh2[3][c];
    part[((size_t)c * totb + boff + b) * 2 + 0] = a;
    part[((size_t)c * totb + boff + b) * 2 + 1] = a2;
  }
}

__global__ __launch_bounds__(64) void reduce_final(
    const float* __restrict__ part, int nblk, int C, float* __restrict__ sums)
{
  const int c = blockIdx.x;
  float s = 0.f, s2 = 0.f;
  for (int b = threadIdx.x; b < nblk; b += 64) {
    s  += part[((size_t)c * nblk + b) * 2 + 0];
    s2 += part[((size_t)c * nblk + b) * 2 + 1];
  }
  for (int off = 32; off > 0; off >>= 1) {
    s  += __shfl_down(s, off);
    s2 += __shfl_down(s2, off);
  }
  if (threadIdx.x == 0) { sums[c] = s; sums[C + c] = s2; }
}

// ---------------- stats -> per-channel affine ----------------
__global__ __launch_bounds__(64) void aff_k(
    const float* __restrict__ st, const float* __restrict__ bias,
    float cnt_inv, int creal, float* __restrict__ a, float* __restrict__ c)
{
  int t = threadIdx.x;
  float mean = st[t] * cnt_inv;
  float var  = st[64 + t] * cnt_inv - mean * mean;
  float inv  = rsqrtf(var + EPSV);
  bool ok = t < creal;
  a[t] = ok ? inv : 0.f;
  c[t] = ok ? (-mean * inv + bias[t]) : 0.f;
}

// ---------------- weight repack: w[CO][CIN][125] fp32 -> wt[125][COP][64] ---
__global__ __launch_bounds__(256) void repack_k(
    const float* __restrict__ w, short* __restrict__ wt,
    int CO, int CIN, int COP)
{
  long total = 125L * COP * 64;
  for (long idx = (long)blockIdx.x * 256 + threadIdx.x; idx < total;
       idx += (long)gridDim.x * 256) {
    int tap = (int)(idx / (COP * 64));
    int r   = (int)(idx % (COP * 64));
    int co = r >> 6, ci = r & 63;
    float v = (co < CO && ci < CIN) ? w[((size_t)co * CIN + ci) * 125 + tap] : 0.f;
    wt[idx] = f2bf(v);
  }
}

// ---------------- w0 repack: w0[52][125] -> w0t[64 co][128 k] ---------------
__global__ __launch_bounds__(256) void repack_w0(
    const float* __restrict__ w, short* __restrict__ wt)
{
  for (int idx = blockIdx.x * 256 + threadIdx.x; idx < 64 * 128;
       idx += gridDim.x * 256) {
    int co = idx >> 7, k = idx & 127;
    float v = (co < 52 && k < 125) ? w[co * 125 + k] : 0.f;
    wt[idx] = f2bf(v);
  }
}

// ---------------- conv0 MFMA: CIN=1, K=125 taps, BN(x) on stage -------------
__global__ __launch_bounds__(256) void conv0_mfma(
    const float* __restrict__ x, const short* __restrict__ w0t,
    const float* __restrict__ stats, short* __restrict__ out,
    int n_in0, int n_out0)
{
  constexpr int IN = 64, OUT = 33;
  constexpr float CNTI = 1.0f / ((float)NB * IN * IN * IN);
  __shared__ __align__(16) char slab[64 * 256];

  const int tid = threadIdx.x;
  const int wv = tid >> 6, ln = tid & 63;
  const int cs = ln >> 4;
  const int ntile0 = blockIdx.x * 64;
  const int od = blockIdx.y;
  const int img = blockIdx.z;

  const float mean = stats[0] * CNTI;
  const float inv  = rsqrtf(stats[1] * CNTI - mean * mean + EPSV);

  bf16x8 afr[4];
  {
    const short* wrow = w0t + (wv * 16 + (ln & 15)) * 128 + cs * 8;
    #pragma unroll
    for (int ks = 0; ks < 4; ++ks) afr[ks] = *(const bf16x8*)(wrow + ks * 32);
  }

  const float* xi = x + (size_t)(n_in0 + img) * (IN * IN * IN);
  const int id_base = 2 * od - 3;
  for (int u = tid; u < 1024; u += 256) {
    const int nl = u >> 4, s = u & 15;
    const int ng = ntile0 + nl;
    const int oh = ng / OUT, ow = ng - oh * OUT;
    const bool nok = ng < OUT * OUT;
    const int ih_base = 2 * oh - 3, iw_base = 2 * ow - 3;
    bf16x8 pk;
    #pragma unroll
    for (int e = 0; e < 8; ++e) {
      const int k = s * 8 + e;
      float f = 0.f;
      if (nok && k < 125) {
        const int kd = k / 25, r = k - kd * 25;
        const int kh = r / 5, kw = r - kh * 5;
        const int id = id_base + kd, ih = ih_base + kh, iw = iw_base + kw;
        if ((unsigned)id < (unsigned)IN && (unsigned)ih < (unsigned)IN &&
            (unsigned)iw < (unsigned)IN)
          f = (xi[((size_t)id * IN + ih) * IN + iw] - mean) * inv;
      }
      pk[e] = f2bf(f);
    }
    const int slot = (s & 8) | ((s & 7) ^ (nl & 7));
    *(bf16x8*)(slab + nl * 256 + slot * 16) = pk;
  }
  __syncthreads();

  const int nl = ln & 15;
  #pragma unroll
  for (int nt = 0; nt < 4; ++nt) {
    f32x4 acc = (f32x4){0.f, 0.f, 0.f, 0.f};
    const int nn = nt * 16 + nl;
    #pragma unroll
    for (int ks = 0; ks < 4; ++ks) {
      const int s = ks * 4 + cs;
      const int slot = (s & 8) | ((s & 7) ^ (nn & 7));
      bf16x8 b = *(const bf16x8*)(slab + nn * 256 + slot * 16);
      acc = __builtin_amdgcn_mfma_f32_16x16x32_bf16(afr[ks], b, acc, 0, 0, 0);
    }
    const int ng = ntile0 + nn;
    if (ng < OUT * OUT) {
      const int oh = ng / OUT, ow = ng - oh * OUT;
      short4v pk;
      #pragma unroll
      for (int r = 0; r < 4; ++r) pk[r] = f2bf(acc[r]);
      size_t base = ((((size_t)(n_out0 + img) * OUT + od) * OUT + oh) * OUT + ow) * 64;
      *(short4v*)(out + base + wv * 16 + cs * 4) = pk;
    }
  }
}

// ---------------- slab swizzle ----------------
__device__ inline int swz(int lin, int cs) {
  int row = lin >> 1;
  int slot = (((lin & 1) << 2) | cs) ^ (row & 7);
  return row * 128 + slot * 16;
}

// ---------------- main conv: r20 body + T14 cross-phase register prefetch --
// 4 waves = 4 m-tiles; BN+ReLU applied at ds_write. ONLY change vs r20/r23:
// (ch,kd) flattened to 10 phases; each phase's global loads are issued in the
// PREVIOUS phase (before the compute barrier) so their L2 latency hides under
// MFMA compute instead of sitting between the two barriers.
template<int IN, int OUT, int OHG>
__global__ __launch_bounds__(256) void conv_m4(
    const short* __restrict__ yin, const short* __restrict__ wt,
    const float* __restrict__ affa, const float* __restrict__ affc,
    short* __restrict__ yout, int n_out0)
{
  constexpr int W = 2 * OUT + 3;
  constexpr int H = 2 * OHG + 3;
  constexpr int LIN = H * W;
  constexpr int ROWS = (LIN + 1) / 2;
  constexpr int NT = (OHG * OUT + 15) / 16;
  constexpr int OHT = (OUT + OHG - 1) / OHG;
  constexpr int LINM = LIN - 1 - 4 * W - 4;
  constexpr int P = (LIN * 4 + 255) / 256;

  __shared__ __align__(16) char slab[ROWS * 128];
  __shared__ float s_a[64], s_c[64];

  const int tid = threadIdx.x;
  const int wv = tid >> 6, ln = tid & 63;
  const int nl = ln & 15, cs = ln >> 4;

  // XCD-chunked decode: consecutive lin share img & adjacent od.
  int lin;
  if (gridDim.x & 7) lin = blockIdx.x;
  else {
    const int q = gridDim.x >> 3;
    lin = (blockIdx.x & 7) * q + (blockIdx.x >> 3);
  }
  const int oht = lin % OHT;
  const int t2  = lin / OHT;
  const int od  = t2 % OUT;
  const int nimg = t2 / OUT;
  const int oh0 = oht * OHG;

  if (tid < 64) { s_a[tid] = affa[tid]; s_c[tid] = affc[tid]; }

  int lb[NT]; bool vld[NT]; size_t obase[NT];
  #pragma unroll
  for (int nt = 0; nt < NT; ++nt) {
    int n = nt * 16 + nl;
    int ohl = n / OUT, ow = n - ohl * OUT;
    vld[nt] = (n < OHG * OUT) && (oh0 + ohl < OUT);
    int l = 2 * ohl * W + 2 * ow;
    lb[nt] = (l > LINM) ? LINM : l;
    obase[nt] = ((((size_t)(n_out0 + nimg) * OUT + od) * OUT + (oh0 + ohl)) * OUT + ow) * 64;
  }

  f32x4 acc[NT];
  #pragma unroll
  for (int nt = 0; nt < NT; ++nt) acc[nt] = (f32x4){0.f, 0.f, 0.f, 0.f};

  const int id_base = 2 * od - 3;
  const int ih_base = 2 * oh0 - 3;

  // ---- prefetch registers for one phase's stage data ----
  bf16x8 pf[P];
  bool   pfb[P];
  {  // prologue: load phase 0 (ch=0, kd=0)
    const int id = id_base + 0;
    const bool dok = (unsigned)id < (unsigned)IN;
    #pragma unroll
    for (int p = 0; p < P; ++p) {
      int u = tid + p * 256;
      bool ok = false;
      bf16x8 v = {0, 0, 0, 0, 0, 0, 0, 0};
      if (u < LIN * 4) {
        int l = u >> 2, cs2 = u & 3;
        int hl = l / W, wl = l - hl * W;
        int ih = ih_base + hl, iw = wl - 3;
        ok = dok && (unsigned)ih < (unsigned)IN && (unsigned)iw < (unsigned)IN;
        if (ok)
          v = *(const bf16x8*)(yin + ((((size_t)nimg * IN + id) * IN + ih) * IN + iw) * 64
                               + cs2 * 8);
      }
      pf[p] = v; pfb[p] = ok;
    }
  }

  #pragma unroll 1
  for (int ph = 0; ph < 10; ++ph) {
    const int ch = ph / 5;
    const int kd = ph - ch * 5;
    __syncthreads();   // slab free (previous compute done); s_a visible
    // ---- write current phase from prefetched regs (affine at write) ----
    #pragma unroll
    for (int p = 0; p < P; ++p) {
      int u = tid + p * 256;
      if (u < LIN * 4) {
        int l = u >> 2, cs2 = u & 3;
        bf16x8 pk = {0, 0, 0, 0, 0, 0, 0, 0};
        if (pfb[p]) {
          #pragma unroll
          for (int e = 0; e < 8; ++e) {
            int c = ch * 32 + cs2 * 8 + e;
            pk[e] = f2bf(fmaxf(s_a[c] * bf2f(pf[p][e]) + s_c[c], 0.f));
          }
        }
        *(bf16x8*)(slab + swz(l, cs2)) = pk;
      }
    }
    // ---- issue NEXT phase's loads; latency hides under compute below ----
    if (ph < 9) {
      const int ch2 = (ph + 1) / 5;
      const int kd2 = (ph + 1) - ch2 * 5;
      const int id = id_base + kd2;
      const bool dok = (unsigned)id < (unsigned)IN;
      #pragma unroll
      for (int p = 0; p < P; ++p) {
        int u = tid + p * 256;
        bool ok = false;
        bf16x8 v = {0, 0, 0, 0, 0, 0, 0, 0};
        if (u < LIN * 4) {
          int l = u >> 2, cs2 = u & 3;
          int hl = l / W, wl = l - hl * W;
          int ih = ih_base + hl, iw = wl - 3;
          ok = dok && (unsigned)ih < (unsigned)IN && (unsigned)iw < (unsigned)IN;
          if (ok)
            v = *(const bf16x8*)(yin + ((((size_t)nimg * IN + id) * IN + ih) * IN + iw) * 64
                                 + ch2 * 32 + cs2 * 8);
        }
        pf[p] = v; pfb[p] = ok;
      }
      __builtin_amdgcn_sched_barrier(0);   // pin load issue before compute
    }
    __syncthreads();   // slab ready
    // ---- compute: per kh, 5 A-frags (this wave's m-tile), NTx5 ds+MFMA ----
    for (int kh = 0; kh < 5; ++kh) {
      const int tapb = (kd * 5 + kh) * 5;
      bf16x8 afr[5];
      #pragma unroll
      for (int kw = 0; kw < 5; ++kw)
        afr[kw] = *(const bf16x8*)(
            wt + ((size_t)(tapb + kw) * 64 + wv * 16 + nl) * 64 + ch * 32 + cs * 8);
      #pragma unroll
      for (int nt = 0; nt < NT; ++nt) {
        const int lin0 = lb[nt] + kh * W;
        #pragma unroll
        for (int kw = 0; kw < 5; ++kw) {
          bf16x8 b = *(const bf16x8*)(slab + swz(lin0 + kw, cs));
          acc[nt] = __builtin_amdgcn_mfma_f32_16x16x32_bf16(
              afr[kw], b, acc[nt], 0, 0, 0);
        }
      }
    }
  }

  #pragma unroll
  for (int nt = 0; nt < NT; ++nt) {
    if (!vld[nt]) continue;
    short4v pk;
    #pragma unroll
    for (int r = 0; r < 4; ++r) pk[r] = f2bf(acc[nt][r]);
    *(short4v*)(yout + obase[nt] + wv * 16 + cs * 4) = pk;
  }
}

// ---------------- conv3: M-split, CO=16 (proven r5 path) -------------------
__global__ __launch_bounds__(256) void conv3_m(
    const short* __restrict__ yin, const short* __restrict__ wt,
    const float* __restrict__ affa, const float* __restrict__ affc,
    short* __restrict__ yout)
{
  constexpr int IN = 10, OUT = 6;
  constexpr int W = 15, LIN = 225, ROWS = 113;
  constexpr int LINM = LIN - 1 - 4 * W - 4;
  __shared__ __align__(16) char slab[ROWS * 128];
  __shared__ float s_a[64], s_c[64];

  const int tid = threadIdx.x, wv = tid >> 6, ln = tid & 63;
  const int nl = ln & 15, cs = ln >> 4;
  const int od = blockIdx.x, nimg = blockIdx.y;

  if (tid < 64) { s_a[tid] = affa[tid]; s_c[tid] = affc[tid]; }

  const int nn = wv * 16 + nl;
  const bool act = wv < 3;
  const bool vld = act && nn < 36;
  int ohl = nn / 6, ow = nn - ohl * 6;
  int lb = 2 * ohl * W + 2 * ow;
  if (lb > LINM) lb = LINM;
  const size_t obase = ((((size_t)nimg * 6 + od) * 6 + ohl) * 6 + ow) * 16;

  f32x4 acc = (f32x4){0.f, 0.f, 0.f, 0.f};
  const int id_base = 2 * od - 3;

  for (int ch = 0; ch < 2; ++ch) {
    for (int kd = 0; kd < 5; ++kd) {
      const int id = id_base + kd;
      const bool dok = (unsigned)id < (unsigned)IN;
      __syncthreads();
      for (int u = tid; u < 900; u += 256) {
        int l = u >> 2, cs2 = u & 3;
        int hl = l / 15, wl = l - hl * 15;
        int ih = hl - 3, iw = wl - 3;
        bf16x8 pk;
        if (dok && (unsigned)ih < (unsigned)IN && (unsigned)iw < (unsigned)IN) {
          bf16x8 ld = *(const bf16x8*)(yin + ((((size_t)nimg * IN + id) * IN + ih) * IN + iw) * 64
                                       + ch * 32 + cs2 * 8);
          #pragma unroll
          for (int e = 0; e < 8; ++e) {
            int c = ch * 32 + cs2 * 8 + e;
            pk[e] = f2bf(fmaxf(s_a[c] * bf2f(ld[e]) + s_c[c], 0.f));
          }
        } else {
          #pragma unroll
          for (int e = 0; e < 8; ++e) pk[e] = 0;
        }
        *(bf16x8*)(slab + swz(l, cs2)) = pk;
      }
      __syncthreads();
      if (act) {
        for (int kh = 0; kh < 5; ++kh) {
          const int tapb = (kd * 5 + kh) * 5;
          bf16x8 afr[5];
          #pragma unroll
          for (int kw = 0; kw < 5; ++kw)
            afr[kw] = *(const bf16x8*)(wt + ((size_t)(tapb + kw) * 16 + nl) * 64
                                       + ch * 32 + cs * 8);
          #pragma unroll
          for (int kw = 0; kw < 5; ++kw) {
            bf16x8 b = *(const bf16x8*)(slab + swz(lb + kh * W + kw, cs));
            acc = __builtin_amdgcn_mfma_f32_16x16x32_bf16(afr[kw], b, acc, 0, 0, 0);
          }
        }
      }
    }
  }
  if (vld) {
    short4v pk;
    #pragma unroll
    for (int r = 0; r < 4; ++r) pk[r] = f2bf(acc[r]);
    *(short4v*)(yout + obase + cs * 4) = pk;
  }
}

// ---------------- global avg pool + affine batch-dim BN (y3 CL-16) --------
__global__ __launch_bounds__(320) void pool_bn(
    const short* __restrict__ y3, const float* __restrict__ gamma,
    const float* __restrict__ beta, float* __restrict__ out)
{
  __shared__ float pool[320];
  const int t = threadIdx.x;
  const int n = t / 10, c = t % 10;
  const short* p = y3 + (size_t)n * 216 * 16 + c;
  float s = 0.f;
  for (int i = 0; i < 216; ++i) s += bf2f(p[i * 16]);
  const float pv = s * (1.0f / 216.0f);
  pool[t] = pv;
  __syncthreads();
  float m = 0.f, m2 = 0.f;
  for (int nn = 0; nn < 32; ++nn) {
    float v = pool[nn * 10 + c];
    m += v; m2 += v * v;
  }
  m *= (1.0f / 32.0f);
  m2 = m2 * (1.0f / 32.0f) - m * m;
  out[t] = (pv - m) * rsqrtf(m2 + EPSV) * gamma[c] + beta[c];
}

// ---------------- launcher ----------------
extern "C" void kernel_launch(void* const* d_in, const int* in_sizes, int n_in,
                              void* d_out, int out_size, void* d_ws, size_t ws_size,
                              hipStream_t stream)
{
  const float* x  = (const float*)d_in[0];
  const float* w0 = (const float*)d_in[1];
  const float* b0 = (const float*)d_in[2];
  const float* w1 = (const float*)d_in[3];
  const float* b1 = (const float*)d_in[4];
  const float* w2 = (const float*)d_in[5];
  const float* b2 = (const float*)d_in[6];
  const float* w3 = (const float*)d_in[7];
  const float* gamma = (const float*)d_in[8];
  const float* beta  = (const float*)d_in[9];
  float* out = (float*)d_out;

  char* base = (char*)d_ws;
  size_t off = 0;
  auto alloc = [&](size_t bytes) -> void* {
    void* p = base + off;
    off = (off + bytes + 255) & ~(size_t)255;
    return p;
  };
  short* y1  = (short*)alloc((size_t)32 * 5832 * 64 * 2);   // 23.9 MB
  short* y2  = (short*)alloc((size_t)32 * 1000 * 64 * 2);   //  4.1 MB
  short* y3  = (short*)alloc((size_t)32 * 216 * 16 * 2);    //  0.22 MB
  short* w1t = (short*)alloc((size_t)125 * 64 * 64 * 2);    //  1.0 MB
  short* w2t = (short*)alloc((size_t)125 * 64 * 64 * 2);
  short* w3t = (short*)alloc((size_t)125 * 16 * 64 * 2);
  short* w0t = (short*)alloc((size_t)64 * 128 * 2);
  float* st_in = (float*)alloc(1024);
  float* st0 = (float*)alloc(1024);
  float* st1 = (float*)alloc(1024);
  float* st2 = (float*)alloc(1024);
  float* a0 = (float*)alloc(256); float* c0 = (float*)alloc(256);
  float* a1 = (float*)alloc(256); float* c1 = (float*)alloc(256);
  float* a2 = (float*)alloc(256); float* c2 = (float*)alloc(256);
  float* part = (float*)alloc(64 * 1024 * 2 * 4);            // 512 KB
  short* y0 = (short*)(base + off);                          // remaining
  size_t rem = (ws_size > off + 256) ? (ws_size - off - 256) : 0;
  const size_t Y0_IMG = (size_t)35937 * 64;                  // CL64
  int CH;
  if      (rem >= Y0_IMG * 32 * 2) CH = 32;
  else if (rem >= Y0_IMG * 16 * 2) CH = 16;
  else if (rem >= Y0_IMG * 8 * 2)  CH = 8;
  else if (rem >= Y0_IMG * 4 * 2)  CH = 4;
  else if (rem >= Y0_IMG * 2 * 2)  CH = 2;
  else                             CH = 1;
  const int nch = 32 / CH;

  repack_k<<<512, 256, 0, stream>>>(w1, w1t, 52, 52, 64);
  repack_k<<<512, 256, 0, stream>>>(w2, w2t, 52, 52, 64);
  repack_k<<<256, 256, 0, stream>>>(w3, w3t, 10, 52, 16);
  repack_w0<<<32, 256, 0, stream>>>(w0, w0t);

  reduce_partial_f32<<<128, 256, 0, stream>>>(x, 64 * 64 * 64, part, 128, 0);
  reduce_final<<<1, 64, 0, stream>>>(part, 128, 1, st_in);

  const float cnt0 = 1.0f / ((float)NB * 35937.0f);
  const float cnt1 = 1.0f / ((float)NB * 5832.0f);
  const float cnt2 = 1.0f / ((float)NB * 1000.0f);

  if (CH == 32) {
    conv0_mfma<<<dim3(18, 33, 32), 256, 0, stream>>>(x, w0t, st_in, y0, 0, 0);
    reduce_cl<<<1024, 256, 0, stream>>>(y0, (long)32 * 35937, part, 1024, 0);
    reduce_final<<<64, 64, 0, stream>>>(part, 1024, 64, st0);
    aff_k<<<1, 64, 0, stream>>>(st0, b0, cnt0, 52, a0, c0);
    conv_m4<33, 18, 2><<<9 * 18 * 32, 256, 0, stream>>>(
        y0, w1t, a0, c0, y1, 0);
  } else {
    for (int ck = 0; ck < nch; ++ck) {
      conv0_mfma<<<dim3(18, 33, CH), 256, 0, stream>>>(x, w0t, st_in, y0, ck * CH, 0);
      reduce_cl<<<32, 256, 0, stream>>>(y0, (long)CH * 35937, part, nch * 32, ck * 32);
    }
    reduce_final<<<64, 64, 0, stream>>>(part, nch * 32, 64, st0);
    aff_k<<<1, 64, 0, stream>>>(st0, b0, cnt0, 52, a0, c0);
    for (int ck = 0; ck < nch; ++ck) {
      conv0_mfma<<<dim3(18, 33, CH), 256, 0, stream>>>(x, w0t, st_in, y0, ck * CH, 0);
      conv_m4<33, 18, 2><<<9 * 18 * CH, 256, 0, stream>>>(
          y0, w1t, a0, c0, y1, ck * CH);
    }
  }

  reduce_cl<<<256, 256, 0, stream>>>(y1, (long)32 * 5832, part, 256, 0);
  reduce_final<<<64, 64, 0, stream>>>(part, 256, 64, st1);
  aff_k<<<1, 64, 0, stream>>>(st1, b1, cnt1, 52, a1, c1);

  conv_m4<18, 10, 4><<<3 * 10 * 32, 256, 0, stream>>>(
      y1, w2t, a1, c1, y2, 0);

  reduce_cl<<<32, 256, 0, stream>>>(y2, (long)32 * 1000, part, 32, 0);
  reduce_final<<<64, 64, 0, stream>>>(part, 32, 64, st2);
  aff_k<<<1, 64, 0, stream>>>(st2, b2, cnt2, 52, a2, c2);

  conv3_m<<<dim3(6, 32), 256, 0, stream>>>(y2, w3t, a2, c2, y3);

  pool_bn<<<1, 320, 0, stream>>>(y3, gamma, beta, out);
}

// Round 25
// 1303.510 us; speedup vs baseline: 1.0364x; 1.0364x over previous
//
#include <hip/hip_runtime.h>
#include <hip/hip_bf16.h>

#define EPSV 1e-5f
constexpr int NB = 32;

typedef short bf16x8 __attribute__((ext_vector_type(8)));
typedef short short4v __attribute__((ext_vector_type(4)));
typedef float f32x4 __attribute__((ext_vector_type(4)));

__device__ inline float bf2f(short s) {
  return __uint_as_float(((unsigned)(unsigned short)s) << 16);
}
__device__ inline short f2bf(float f) {
  unsigned u = __float_as_uint(f);
  unsigned r = (u + 0x7FFFu + ((u >> 16) & 1u)) >> 16;
  return (short)r;
}

// ---------------- x stats (NCDHW, C=1) ----------------
__global__ __launch_bounds__(256) void reduce_partial_f32(
    const float* __restrict__ in, int spatial, float* __restrict__ part,
    int totb, int boff)
{
  const int b = blockIdx.x;
  const int nblk = gridDim.x;
  float s = 0.f, s2 = 0.f;
  for (int n = 0; n < NB; ++n) {
    const float* p = in + (size_t)n * spatial;
    for (int i = b * 256 + threadIdx.x; i < spatial; i += nblk * 256) {
      float v = p[i];
      s += v; s2 += v * v;
    }
  }
  __shared__ float sh[256], sh2[256];
  int tid = threadIdx.x;
  sh[tid] = s; sh2[tid] = s2;
  __syncthreads();
  for (int off = 128; off > 0; off >>= 1) {
    if (tid < off) { sh[tid] += sh[tid + off]; sh2[tid] += sh2[tid + off]; }
    __syncthreads();
  }
  if (tid == 0) {
    part[(size_t)(boff + b) * 2 + 0] = sh[0];
    part[(size_t)(boff + b) * 2 + 1] = sh2[0];
  }
}

// ---------------- channels-last (rowlen 64) per-channel stats --------------
__global__ __launch_bounds__(256) void reduce_cl(
    const short* __restrict__ y, long nrows,
    float* __restrict__ part, int totb, int boff)
{
  const int b = blockIdx.x, nblk = gridDim.x;
  const int c = threadIdx.x & 63, seg = threadIdx.x >> 6;
  float s = 0.f, s2 = 0.f;
  for (long r = (long)b * 4 + seg; r < nrows; r += (long)nblk * 4) {
    float v = bf2f(y[r * 64 + c]);
    s += v; s2 += v * v;
  }
  __shared__ float sh[4][64], sh2[4][64];
  sh[seg][c] = s; sh2[seg][c] = s2;
  __syncthreads();
  if (seg == 0) {
    float a = sh[0][c] + sh[1][c] + sh[2][c] + sh[3][c];
    float a2 = sh2[0][c] + sh2[1][c] + sh2[2][c] + sh2[3][c];
    part[((size_t)c * totb + boff + b) * 2 + 0] = a;
    part[((size_t)c * totb + boff + b) * 2 + 1] = a2;
  }
}

__global__ __launch_bounds__(64) void reduce_final(
    const float* __restrict__ part, int nblk, int C, float* __restrict__ sums)
{
  const int c = blockIdx.x;
  float s = 0.f, s2 = 0.f;
  for (int b = threadIdx.x; b < nblk; b += 64) {
    s  += part[((size_t)c * nblk + b) * 2 + 0];
    s2 += part[((size_t)c * nblk + b) * 2 + 1];
  }
  for (int off = 32; off > 0; off >>= 1) {
    s  += __shfl_down(s, off);
    s2 += __shfl_down(s2, off);
  }
  if (threadIdx.x == 0) { sums[c] = s; sums[C + c] = s2; }
}

// ---------------- stats -> per-channel affine ----------------
__global__ __launch_bounds__(64) void aff_k(
    const float* __restrict__ st, const float* __restrict__ bias,
    float cnt_inv, int creal, float* __restrict__ a, float* __restrict__ c)
{
  int t = threadIdx.x;
  float mean = st[t] * cnt_inv;
  float var  = st[64 + t] * cnt_inv - mean * mean;
  float inv  = rsqrtf(var + EPSV);
  bool ok = t < creal;
  a[t] = ok ? inv : 0.f;
  c[t] = ok ? (-mean * inv + bias[t]) : 0.f;
}

// ---------------- weight repack: w[CO][CIN][125] fp32 -> wt[125][COP][64] ---
__global__ __launch_bounds__(256) void repack_k(
    const float* __restrict__ w, short* __restrict__ wt,
    int CO, int CIN, int COP)
{
  long total = 125L * COP * 64;
  for (long idx = (long)blockIdx.x * 256 + threadIdx.x; idx < total;
       idx += (long)gridDim.x * 256) {
    int tap = (int)(idx / (COP * 64));
    int r   = (int)(idx % (COP * 64));
    int co = r >> 6, ci = r & 63;
    float v = (co < CO && ci < CIN) ? w[((size_t)co * CIN + ci) * 125 + tap] : 0.f;
    wt[idx] = f2bf(v);
  }
}

// ---------------- w0 repack: w0[52][125] -> w0t[64 co][128 k] ---------------
__global__ __launch_bounds__(256) void repack_w0(
    const float* __restrict__ w, short* __restrict__ wt)
{
  for (int idx = blockIdx.x * 256 + threadIdx.x; idx < 64 * 128;
       idx += gridDim.x * 256) {
    int co = idx >> 7, k = idx & 127;
    float v = (co < 52 && k < 125) ? w[co * 125 + k] : 0.f;
    wt[idx] = f2bf(v);
  }
}

// ---------------- conv0 MFMA: CIN=1, K=125 taps, BN(x) on stage -------------
__global__ __launch_bounds__(256) void conv0_mfma(
    const float* __restrict__ x, const short* __restrict__ w0t,
    const float* __restrict__ stats, short* __restrict__ out,
    int n_in0, int n_out0)
{
  constexpr int IN = 64, OUT = 33;
  constexpr float CNTI = 1.0f / ((float)NB * IN * IN * IN);
  __shared__ __align__(16) char slab[64 * 256];

  const int tid = threadIdx.x;
  const int wv = tid >> 6, ln = tid & 63;
  const int cs = ln >> 4;
  const int ntile0 = blockIdx.x * 64;
  const int od = blockIdx.y;
  const int img = blockIdx.z;

  const float mean = stats[0] * CNTI;
  const float inv  = rsqrtf(stats[1] * CNTI - mean * mean + EPSV);

  bf16x8 afr[4];
  {
    const short* wrow = w0t + (wv * 16 + (ln & 15)) * 128 + cs * 8;
    #pragma unroll
    for (int ks = 0; ks < 4; ++ks) afr[ks] = *(const bf16x8*)(wrow + ks * 32);
  }

  const float* xi = x + (size_t)(n_in0 + img) * (IN * IN * IN);
  const int id_base = 2 * od - 3;
  for (int u = tid; u < 1024; u += 256) {
    const int nl = u >> 4, s = u & 15;
    const int ng = ntile0 + nl;
    const int oh = ng / OUT, ow = ng - oh * OUT;
    const bool nok = ng < OUT * OUT;
    const int ih_base = 2 * oh - 3, iw_base = 2 * ow - 3;
    bf16x8 pk;
    #pragma unroll
    for (int e = 0; e < 8; ++e) {
      const int k = s * 8 + e;
      float f = 0.f;
      if (nok && k < 125) {
        const int kd = k / 25, r = k - kd * 25;
        const int kh = r / 5, kw = r - kh * 5;
        const int id = id_base + kd, ih = ih_base + kh, iw = iw_base + kw;
        if ((unsigned)id < (unsigned)IN && (unsigned)ih < (unsigned)IN &&
            (unsigned)iw < (unsigned)IN)
          f = (xi[((size_t)id * IN + ih) * IN + iw] - mean) * inv;
      }
      pk[e] = f2bf(f);
    }
    const int slot = (s & 8) | ((s & 7) ^ (nl & 7));
    *(bf16x8*)(slab + nl * 256 + slot * 16) = pk;
  }
  __syncthreads();

  const int nl = ln & 15;
  #pragma unroll
  for (int nt = 0; nt < 4; ++nt) {
    f32x4 acc = (f32x4){0.f, 0.f, 0.f, 0.f};
    const int nn = nt * 16 + nl;
    #pragma unroll
    for (int ks = 0; ks < 4; ++ks) {
      const int s = ks * 4 + cs;
      const int slot = (s & 8) | ((s & 7) ^ (nn & 7));
      bf16x8 b = *(const bf16x8*)(slab + nn * 256 + slot * 16);
      acc = __builtin_amdgcn_mfma_f32_16x16x32_bf16(afr[ks], b, acc, 0, 0, 0);
    }
    const int ng = ntile0 + nn;
    if (ng < OUT * OUT) {
      const int oh = ng / OUT, ow = ng - oh * OUT;
      short4v pk;
      #pragma unroll
      for (int r = 0; r < 4; ++r) pk[r] = f2bf(acc[r]);
      size_t base = ((((size_t)(n_out0 + img) * OUT + od) * OUT + oh) * OUT + ow) * 64;
      *(short4v*)(out + base + wv * 16 + cs * 4) = pk;
    }
  }
}

// ---------------- slab swizzle ----------------
__device__ inline int swz(int lin, int cs) {
  int row = lin >> 1;
  int slot = (((lin & 1) << 2) | cs) ^ (row & 7);
  return row * 128 + slot * 16;
}

// ---------------- main conv: r20-best M-split body + XCD-chunked 1D grid ---
// 4 waves = 4 m-tiles; each wave computes ALL NT n-tiles; BN+ReLU on stage.
// Best-measured configuration (r20/r23: total ~1304us, conv1 ~693us).
template<int IN, int OUT, int OHG>
__global__ __launch_bounds__(256) void conv_m4(
    const short* __restrict__ yin, const short* __restrict__ wt,
    const float* __restrict__ affa, const float* __restrict__ affc,
    short* __restrict__ yout, int n_out0)
{
  constexpr int W = 2 * OUT + 3;
  constexpr int H = 2 * OHG + 3;
  constexpr int LIN = H * W;
  constexpr int ROWS = (LIN + 1) / 2;
  constexpr int NT = (OHG * OUT + 15) / 16;
  constexpr int OHT = (OUT + OHG - 1) / OHG;
  constexpr int LINM = LIN - 1 - 4 * W - 4;

  __shared__ __align__(16) char slab[ROWS * 128];
  __shared__ float s_a[64], s_c[64];

  const int tid = threadIdx.x;
  const int wv = tid >> 6, ln = tid & 63;
  const int nl = ln & 15, cs = ln >> 4;

  // XCD-chunked decode: consecutive lin share img & adjacent od.
  int lin;
  if (gridDim.x & 7) lin = blockIdx.x;
  else {
    const int q = gridDim.x >> 3;
    lin = (blockIdx.x & 7) * q + (blockIdx.x >> 3);
  }
  const int oht = lin % OHT;
  const int t2  = lin / OHT;
  const int od  = t2 % OUT;
  const int nimg = t2 / OUT;
  const int oh0 = oht * OHG;

  if (tid < 64) { s_a[tid] = affa[tid]; s_c[tid] = affc[tid]; }

  int lb[NT]; bool vld[NT]; size_t obase[NT];
  #pragma unroll
  for (int nt = 0; nt < NT; ++nt) {
    int n = nt * 16 + nl;
    int ohl = n / OUT, ow = n - ohl * OUT;
    vld[nt] = (n < OHG * OUT) && (oh0 + ohl < OUT);
    int l = 2 * ohl * W + 2 * ow;
    lb[nt] = (l > LINM) ? LINM : l;
    obase[nt] = ((((size_t)(n_out0 + nimg) * OUT + od) * OUT + (oh0 + ohl)) * OUT + ow) * 64;
  }

  f32x4 acc[NT];
  #pragma unroll
  for (int nt = 0; nt < NT; ++nt) acc[nt] = (f32x4){0.f, 0.f, 0.f, 0.f};

  const int id_base = 2 * od - 3;
  const int ih_base = 2 * oh0 - 3;

  for (int ch = 0; ch < 2; ++ch) {
    for (int kd = 0; kd < 5; ++kd) {
      __syncthreads();
      {  // ---- stage: relu(a*y + c), one (cin-half, kd) plane ----
        const int id = id_base + kd;
        const bool dok = (unsigned)id < (unsigned)IN;
        for (int u = tid; u < LIN * 4; u += 256) {
          int l = u >> 2, cs2 = u & 3;
          int hl = l / W, wl = l - hl * W;
          int ih = ih_base + hl;
          int iw = wl - 3;
          bf16x8 pk;
          if (dok && (unsigned)ih < (unsigned)IN && (unsigned)iw < (unsigned)IN) {
            size_t base = ((((size_t)nimg * IN + id) * IN + ih) * IN + iw) * 64
                          + ch * 32 + cs2 * 8;
            bf16x8 ld = *(const bf16x8*)(yin + base);
            #pragma unroll
            for (int e = 0; e < 8; ++e) {
              int c = ch * 32 + cs2 * 8 + e;
              pk[e] = f2bf(fmaxf(s_a[c] * bf2f(ld[e]) + s_c[c], 0.f));
            }
          } else {
            #pragma unroll
            for (int e = 0; e < 8; ++e) pk[e] = 0;
          }
          *(bf16x8*)(slab + swz(l, cs2)) = pk;
        }
      }
      __syncthreads();
      // ---- compute: per kh, 5 A-frags (this wave's m-tile), NTx5 ds+MFMA --
      for (int kh = 0; kh < 5; ++kh) {
        const int tapb = (kd * 5 + kh) * 5;
        bf16x8 afr[5];
        #pragma unroll
        for (int kw = 0; kw < 5; ++kw)
          afr[kw] = *(const bf16x8*)(
              wt + ((size_t)(tapb + kw) * 64 + wv * 16 + nl) * 64 + ch * 32 + cs * 8);
        #pragma unroll
        for (int nt = 0; nt < NT; ++nt) {
          const int lin0 = lb[nt] + kh * W;
          #pragma unroll
          for (int kw = 0; kw < 5; ++kw) {
            bf16x8 b = *(const bf16x8*)(slab + swz(lin0 + kw, cs));
            acc[nt] = __builtin_amdgcn_mfma_f32_16x16x32_bf16(
                afr[kw], b, acc[nt], 0, 0, 0);
          }
        }
      }
    }
  }

  #pragma unroll
  for (int nt = 0; nt < NT; ++nt) {
    if (!vld[nt]) continue;
    short4v pk;
    #pragma unroll
    for (int r = 0; r < 4; ++r) pk[r] = f2bf(acc[nt][r]);
    *(short4v*)(yout + obase[nt] + wv * 16 + cs * 4) = pk;
  }
}

// ---------------- conv3: M-split, CO=16 (proven r5 path) -------------------
__global__ __launch_bounds__(256) void conv3_m(
    const short* __restrict__ yin, const short* __restrict__ wt,
    const float* __restrict__ affa, const float* __restrict__ affc,
    short* __restrict__ yout)
{
  constexpr int IN = 10, OUT = 6;
  constexpr int W = 15, LIN = 225, ROWS = 113;
  constexpr int LINM = LIN - 1 - 4 * W - 4;
  __shared__ __align__(16) char slab[ROWS * 128];
  __shared__ float s_a[64], s_c[64];

  const int tid = threadIdx.x, wv = tid >> 6, ln = tid & 63;
  const int nl = ln & 15, cs = ln >> 4;
  const int od = blockIdx.x, nimg = blockIdx.y;

  if (tid < 64) { s_a[tid] = affa[tid]; s_c[tid] = affc[tid]; }

  const int nn = wv * 16 + nl;
  const bool act = wv < 3;
  const bool vld = act && nn < 36;
  int ohl = nn / 6, ow = nn - ohl * 6;
  int lb = 2 * ohl * W + 2 * ow;
  if (lb > LINM) lb = LINM;
  const size_t obase = ((((size_t)nimg * 6 + od) * 6 + ohl) * 6 + ow) * 16;

  f32x4 acc = (f32x4){0.f, 0.f, 0.f, 0.f};
  const int id_base = 2 * od - 3;

  for (int ch = 0; ch < 2; ++ch) {
    for (int kd = 0; kd < 5; ++kd) {
      const int id = id_base + kd;
      const bool dok = (unsigned)id < (unsigned)IN;
      __syncthreads();
      for (int u = tid; u < 900; u += 256) {
        int l = u >> 2, cs2 = u & 3;
        int hl = l / 15, wl = l - hl * 15;
        int ih = hl - 3, iw = wl - 3;
        bf16x8 pk;
        if (dok && (unsigned)ih < (unsigned)IN && (unsigned)iw < (unsigned)IN) {
          bf16x8 ld = *(const bf16x8*)(yin + ((((size_t)nimg * IN + id) * IN + ih) * IN + iw) * 64
                                       + ch * 32 + cs2 * 8);
          #pragma unroll
          for (int e = 0; e < 8; ++e) {
            int c = ch * 32 + cs2 * 8 + e;
            pk[e] = f2bf(fmaxf(s_a[c] * bf2f(ld[e]) + s_c[c], 0.f));
          }
        } else {
          #pragma unroll
          for (int e = 0; e < 8; ++e) pk[e] = 0;
        }
        *(bf16x8*)(slab + swz(l, cs2)) = pk;
      }
      __syncthreads();
      if (act) {
        for (int kh = 0; kh < 5; ++kh) {
          const int tapb = (kd * 5 + kh) * 5;
          bf16x8 afr[5];
          #pragma unroll
          for (int kw = 0; kw < 5; ++kw)
            afr[kw] = *(const bf16x8*)(wt + ((size_t)(tapb + kw) * 16 + nl) * 64
                                       + ch * 32 + cs * 8);
          #pragma unroll
          for (int kw = 0; kw < 5; ++kw) {
            bf16x8 b = *(const bf16x8*)(slab + swz(lb + kh * W + kw, cs));
            acc = __builtin_amdgcn_mfma_f32_16x16x32_bf16(afr[kw], b, acc, 0, 0, 0);
          }
        }
      }
    }
  }
  if (vld) {
    short4v pk;
    #pragma unroll
    for (int r = 0; r < 4; ++r) pk[r] = f2bf(acc[r]);
    *(short4v*)(yout + obase + cs * 4) = pk;
  }
}

// ---------------- global avg pool + affine batch-dim BN (y3 CL-16) --------
__global__ __launch_bounds__(320) void pool_bn(
    const short* __restrict__ y3, const float* __restrict__ gamma,
    const float* __restrict__ beta, float* __restrict__ out)
{
  __shared__ float pool[320];
  const int t = threadIdx.x;
  const int n = t / 10, c = t % 10;
  const short* p = y3 + (size_t)n * 216 * 16 + c;
  float s = 0.f;
  for (int i = 0; i < 216; ++i) s += bf2f(p[i * 16]);
  const float pv = s * (1.0f / 216.0f);
  pool[t] = pv;
  __syncthreads();
  float m = 0.f, m2 = 0.f;
  for (int nn = 0; nn < 32; ++nn) {
    float v = pool[nn * 10 + c];
    m += v; m2 += v * v;
  }
  m *= (1.0f / 32.0f);
  m2 = m2 * (1.0f / 32.0f) - m * m;
  out[t] = (pv - m) * rsqrtf(m2 + EPSV) * gamma[c] + beta[c];
}

// ---------------- launcher ----------------
extern "C" void kernel_launch(void* const* d_in, const int* in_sizes, int n_in,
                              void* d_out, int out_size, void* d_ws, size_t ws_size,
                              hipStream_t stream)
{
  const float* x  = (const float*)d_in[0];
  const float* w0 = (const float*)d_in[1];
  const float* b0 = (const float*)d_in[2];
  const float* w1 = (const float*)d_in[3];
  const float* b1 = (const float*)d_in[4];
  const float* w2 = (const float*)d_in[5];
  const float* b2 = (const float*)d_in[6];
  const float* w3 = (const float*)d_in[7];
  const float* gamma = (const float*)d_in[8];
  const float* beta  = (const float*)d_in[9];
  float* out = (float*)d_out;

  char* base = (char*)d_ws;
  size_t off = 0;
  auto alloc = [&](size_t bytes) -> void* {
    void* p = base + off;
    off = (off + bytes + 255) & ~(size_t)255;
    return p;
  };
  short* y1  = (short*)alloc((size_t)32 * 5832 * 64 * 2);   // 23.9 MB
  short* y2  = (short*)alloc((size_t)32 * 1000 * 64 * 2);   //  4.1 MB
  short* y3  = (short*)alloc((size_t)32 * 216 * 16 * 2);    //  0.22 MB
  short* w1t = (short*)alloc((size_t)125 * 64 * 64 * 2);    //  1.0 MB
  short* w2t = (short*)alloc((size_t)125 * 64 * 64 * 2);
  short* w3t = (short*)alloc((size_t)125 * 16 * 64 * 2);
  short* w0t = (short*)alloc((size_t)64 * 128 * 2);
  float* st_in = (float*)alloc(1024);
  float* st0 = (float*)alloc(1024);
  float* st1 = (float*)alloc(1024);
  float* st2 = (float*)alloc(1024);
  float* a0 = (float*)alloc(256); float* c0 = (float*)alloc(256);
  float* a1 = (float*)alloc(256); float* c1 = (float*)alloc(256);
  float* a2 = (float*)alloc(256); float* c2 = (float*)alloc(256);
  float* part = (float*)alloc(64 * 1024 * 2 * 4);            // 512 KB
  short* y0 = (short*)(base + off);                          // remaining
  size_t rem = (ws_size > off + 256) ? (ws_size - off - 256) : 0;
  const size_t Y0_IMG = (size_t)35937 * 64;                  // CL64
  int CH;
  if      (rem >= Y0_IMG * 32 * 2) CH = 32;
  else if (rem >= Y0_IMG * 16 * 2) CH = 16;
  else if (rem >= Y0_IMG * 8 * 2)  CH = 8;
  else if (rem >= Y0_IMG * 4 * 2)  CH = 4;
  else if (rem >= Y0_IMG * 2 * 2)  CH = 2;
  else                             CH = 1;
  const int nch = 32 / CH;

  repack_k<<<512, 256, 0, stream>>>(w1, w1t, 52, 52, 64);
  repack_k<<<512, 256, 0, stream>>>(w2, w2t, 52, 52, 64);
  repack_k<<<256, 256, 0, stream>>>(w3, w3t, 10, 52, 16);
  repack_w0<<<32, 256, 0, stream>>>(w0, w0t);

  reduce_partial_f32<<<128, 256, 0, stream>>>(x, 64 * 64 * 64, part, 128, 0);
  reduce_final<<<1, 64, 0, stream>>>(part, 128, 1, st_in);

  const float cnt0 = 1.0f / ((float)NB * 35937.0f);
  const float cnt1 = 1.0f / ((float)NB * 5832.0f);
  const float cnt2 = 1.0f / ((float)NB * 1000.0f);

  if (CH == 32) {
    conv0_mfma<<<dim3(18, 33, 32), 256, 0, stream>>>(x, w0t, st_in, y0, 0, 0);
    reduce_cl<<<1024, 256, 0, stream>>>(y0, (long)32 * 35937, part, 1024, 0);
    reduce_final<<<64, 64, 0, stream>>>(part, 1024, 64, st0);
    aff_k<<<1, 64, 0, stream>>>(st0, b0, cnt0, 52, a0, c0);
    conv_m4<33, 18, 2><<<9 * 18 * 32, 256, 0, stream>>>(
        y0, w1t, a0, c0, y1, 0);
  } else {
    for (int ck = 0; ck < nch; ++ck) {
      conv0_mfma<<<dim3(18, 33, CH), 256, 0, stream>>>(x, w0t, st_in, y0, ck * CH, 0);
      reduce_cl<<<32, 256, 0, stream>>>(y0, (long)CH * 35937, part, nch * 32, ck * 32);
    }
    reduce_final<<<64, 64, 0, stream>>>(part, nch * 32, 64, st0);
    aff_k<<<1, 64, 0, stream>>>(st0, b0, cnt0, 52, a0, c0);
    for (int ck = 0; ck < nch; ++ck) {
      conv0_mfma<<<dim3(18, 33, CH), 256, 0, stream>>>(x, w0t, st_in, y0, ck * CH, 0);
      conv_m4<33, 18, 2><<<9 * 18 * CH, 256, 0, stream>>>(
          y0, w1t, a0, c0, y1, ck * CH);
    }
  }

  reduce_cl<<<256, 256, 0, stream>>>(y1, (long)32 * 5832, part, 256, 0);
  reduce_final<<<64, 64, 0, stream>>>(part, 256, 64, st1);
  aff_k<<<1, 64, 0, stream>>>(st1, b1, cnt1, 52, a1, c1);

  conv_m4<18, 10, 4><<<3 * 10 * 32, 256, 0, stream>>>(
      y1, w2t, a1, c1, y2, 0);

  reduce_cl<<<32, 256, 0, stream>>>(y2, (long)32 * 1000, part, 32, 0);
  reduce_final<<<64, 64, 0, stream>>>(part, 32, 64, st2);
  aff_k<<<1, 64, 0, stream>>>(st2, b2, cnt2, 52, a2, c2);

  conv3_m<<<dim3(6, 32), 256, 0, stream>>>(y2, w3t, a2, c2, y3);

  pool_bn<<<1, 320, 0, stream>>>(y3, gamma, beta, out);
}